// Round 7
// baseline (541.857 us; speedup 1.0000x reference)
//
#include <hip/hip_runtime.h>
#include <hip/hip_cooperative_groups.h>

namespace cg = cooperative_groups;

#define N_ATOMS 8388608
#define N_MOLS  262144
#define TPB     256
#define NBLK    1024            // 1024 x 256 = 262144 threads = N_MOLS
#define APT     32              // 262144 * 32 = N_ATOMS

// ---------------- fused cooperative kernel (low-VGPR variant) ----------------
// Phase A: per-thread serial segment accumulate over 32 contiguous atoms.
//   interior segments (start>0) -> exclusive plain store; head/tail -> atomics.
// Phase B: thread tid owns molecule tid: t = (sum_q + sum_esi) / sum_si.
// Phase C: re-read h (L3-hot) + mol, out = (t[mol] - e) / s.
__global__ __launch_bounds__(TPB) void ce_fused(
    const float4* __restrict__ h4, const float4* __restrict__ q4,
    const int4* __restrict__ mol4,
    float* __restrict__ sum_q, float* __restrict__ sum_si,
    float* __restrict__ sum_esi, float* __restrict__ tmol,
    float4* __restrict__ out4)
{
    cg::grid_group grid = cg::this_grid();
    const int tid = blockIdx.x * TPB + threadIdx.x;

    // ---------------- Phase A ----------------
    int   mcur = 0, cs = 0;
    float aq = 0.f, av = 0.f, ae = 0.f;
    #pragma unroll
    for (int qt = 0; qt < 4; ++qt) {          // 4 quarters x 8 atoms
        float4 hv[4]; float4 qv[2]; int4 mv[2];
        #pragma unroll
        for (int j = 0; j < 4; ++j) hv[j] = h4[tid * 16 + qt * 4 + j];
        #pragma unroll
        for (int j = 0; j < 2; ++j) qv[j] = q4[tid * 8 + qt * 2 + j];
        #pragma unroll
        for (int j = 0; j < 2; ++j) mv[j] = mol4[tid * 8 + qt * 2 + j];
        const float* hf = (const float*)hv;
        const float* qf = (const float*)qv;
        const int*   mi = (const int*)mv;

        #pragma unroll
        for (int k = 0; k < 8; ++k) {
            const int a = qt * 8 + k;
            float siv = 1.0f / hf[2 * k + 1];
            float esv = hf[2 * k] * siv;
            int   m   = mi[k];
            if (a == 0) {
                mcur = m;
            } else if (m != mcur) {
                if (cs > 0) {                  // wholly inside this thread
                    sum_q[mcur]   = aq;
                    sum_si[mcur]  = av;
                    sum_esi[mcur] = ae;
                } else {                       // head partial: may be shared
                    atomicAdd(&sum_q[mcur],   aq);
                    atomicAdd(&sum_si[mcur],  av);
                    atomicAdd(&sum_esi[mcur], ae);
                }
                aq = 0.f; av = 0.f; ae = 0.f;
                cs = a; mcur = m;
            }
            aq += qf[k]; av += siv; ae += esv;
        }
    }
    // tail partial: may be shared with the next thread
    atomicAdd(&sum_q[mcur],   aq);
    atomicAdd(&sum_si[mcur],  av);
    atomicAdd(&sum_esi[mcur], ae);

    __threadfence();
    grid.sync();

    // ---------------- Phase B ----------------
    tmol[tid] = (sum_q[tid] + sum_esi[tid]) / sum_si[tid];

    __threadfence();
    grid.sync();

    // ---------------- Phase C ----------------
    #pragma unroll
    for (int qt = 0; qt < 4; ++qt) {
        float4 hv[4]; int4 mv[2];
        #pragma unroll
        for (int j = 0; j < 4; ++j) hv[j] = h4[tid * 16 + qt * 4 + j];
        #pragma unroll
        for (int j = 0; j < 2; ++j) mv[j] = mol4[tid * 8 + qt * 2 + j];
        const float* hf = (const float*)hv;
        const int*   mi = (const int*)mv;

        float4 o[2]; float* of = (float*)o;
        #pragma unroll
        for (int k = 0; k < 8; ++k)
            of[k] = (tmol[mi[k]] - hf[2 * k]) / hf[2 * k + 1];
        #pragma unroll
        for (int j = 0; j < 2; ++j) out4[tid * 8 + qt * 2 + j] = o[j];
    }
}

// ---------------- fallback: proven 3-kernel path (round-3, passed) ----------
__global__ __launch_bounds__(256) void ce_pass1(
    const float4* __restrict__ h4, const float4* __restrict__ q4,
    const int4* __restrict__ mol4,
    float* __restrict__ sum_q, float* __restrict__ sum_si,
    float* __restrict__ sum_esi)
{
    int t = blockIdx.x * blockDim.x + threadIdx.x;
    float4 ha = h4[t*4+0], hb = h4[t*4+1], hc = h4[t*4+2], hd = h4[t*4+3];
    float4 qa = q4[t*2+0], qb = q4[t*2+1];
    int4   ma = mol4[t*2+0], mb = mol4[t*2+1];

    float e[8]  = {ha.x,ha.z,hb.x,hb.z,hc.x,hc.z,hd.x,hd.z};
    float s[8]  = {ha.y,ha.w,hb.y,hb.w,hc.y,hc.w,hd.y,hd.w};
    float qq[8] = {qa.x,qa.y,qa.z,qa.w,qb.x,qb.y,qb.z,qb.w};
    int   mm[8] = {ma.x,ma.y,ma.z,ma.w,mb.x,mb.y,mb.z,mb.w};

    int mcur = mm[0];
    float aq = 0.f, as = 0.f, ae = 0.f;
    #pragma unroll
    for (int k = 0; k < 8; ++k) {
        float si = 1.0f / s[k];
        if (mm[k] != mcur) {
            atomicAdd(&sum_q[mcur], aq); atomicAdd(&sum_si[mcur], as); atomicAdd(&sum_esi[mcur], ae);
            mcur = mm[k]; aq = 0.f; as = 0.f; ae = 0.f;
        }
        aq += qq[k]; as += si; ae += e[k] * si;
    }
    int lane = threadIdx.x & 63;
    #pragma unroll
    for (int off = 1; off < 64; off <<= 1) {
        int   om = __shfl_up(mcur, off, 64);
        float oq = __shfl_up(aq, off, 64);
        float os = __shfl_up(as, off, 64);
        float oe = __shfl_up(ae, off, 64);
        if (lane >= off && om == mcur) { aq += oq; as += os; ae += oe; }
    }
    int nm = __shfl_down(mcur, 1, 64);
    if (lane == 63 || nm != mcur) {
        atomicAdd(&sum_q[mcur], aq); atomicAdd(&sum_si[mcur], as); atomicAdd(&sum_esi[mcur], ae);
    }
}

__global__ __launch_bounds__(256) void ce_pass2(
    const float* __restrict__ sum_q, const float* __restrict__ sum_si,
    const float* __restrict__ sum_esi, float* __restrict__ t)
{
    int m = blockIdx.x * blockDim.x + threadIdx.x;
    t[m] = (sum_q[m] + sum_esi[m]) / sum_si[m];
}

__global__ __launch_bounds__(256) void ce_pass3(
    const float4* __restrict__ h4, const int4* __restrict__ mol4,
    const float* __restrict__ tmol, float4* __restrict__ out4)
{
    int g = blockIdx.x * 256 + threadIdx.x;
    int4   m4 = mol4[g];
    float4 hA = h4[g*2], hB = h4[g*2+1];
    float4 o;
    o.x = (tmol[m4.x] - hA.x) / hA.y;
    o.y = (tmol[m4.y] - hA.z) / hA.w;
    o.z = (tmol[m4.z] - hB.x) / hB.y;
    o.w = (tmol[m4.w] - hB.z) / hB.w;
    out4[g] = o;
}

extern "C" void kernel_launch(void* const* d_in, const int* in_sizes, int n_in,
                              void* d_out, int out_size, void* d_ws, size_t ws_size,
                              hipStream_t stream) {
    const float4* h4   = (const float4*)d_in[0];
    const float4* q4   = (const float4*)d_in[1];
    const int4*   mol4 = (const int4*)d_in[2];
    float4* out4 = (float4*)d_out;

    float* sum_q   = (float*)d_ws;
    float* sum_si  = sum_q  + N_MOLS;
    float* sum_esi = sum_si + N_MOLS;
    float* tmol    = sum_esi + N_MOLS;

    hipMemsetAsync(d_ws, 0, (size_t)3 * N_MOLS * sizeof(float), stream);

    void* args[] = { (void*)&h4, (void*)&q4, (void*)&mol4, (void*)&sum_q,
                     (void*)&sum_si, (void*)&sum_esi, (void*)&tmol, (void*)&out4 };
    hipError_t err = hipLaunchCooperativeKernel((void*)ce_fused, dim3(NBLK),
                                                dim3(TPB), args, 0, stream);
    if (err != hipSuccess) {
        (void)hipGetLastError();   // clear sticky error, take proven path
        ce_pass1<<<N_ATOMS / (256 * 8), 256, 0, stream>>>(h4, q4, mol4,
                                                          sum_q, sum_si, sum_esi);
        ce_pass2<<<N_MOLS / 256, 256, 0, stream>>>(sum_q, sum_si, sum_esi, tmol);
        ce_pass3<<<N_ATOMS / 4 / 256, 256, 0, stream>>>(h4, mol4, tmol, out4);
    }
}

// Round 8
// 61.684 us; speedup vs baseline: 8.7843x; 8.7843x over previous
//
#include <hip/hip_runtime.h>

#define N_ATOMS 8388608
#define N_MOLS  262144

// Pass 1: 2 atoms/thread, perfectly coalesced loads (h: one float4 = 16B/lane,
// q: float2 = 8B/lane, mol: int2 = 8B/lane). Pair pre-combine (boundary inside
// the pair -> direct atomic flush of atom 0, ~3% of threads), then a 6-step
// segmented inclusive shuffle scan over per-thread pair-partials (keys are
// nondecreasing across lanes => equal keys contiguous => scan exact), and
// segment-tail lanes issue the global atomics (~1M total over 3MB).
__global__ __launch_bounds__(256) void ce_pass1(
    const float4* __restrict__ h4, const float2* __restrict__ q2,
    const int2* __restrict__ mol2,
    float* __restrict__ sum_q, float* __restrict__ sum_si,
    float* __restrict__ sum_esi)
{
    int t = blockIdx.x * blockDim.x + threadIdx.x;   // 0 .. N_ATOMS/2 - 1
    float4 hv = h4[t];          // e0, s0, e1, s1
    float2 qv = q2[t];
    int2   mv = mol2[t];

    float si0 = 1.0f / hv.y, esi0 = hv.x * si0;
    float si1 = 1.0f / hv.w, esi1 = hv.z * si1;

    float aq, as, ae;
    if (mv.x == mv.y) {          // common: whole pair in one molecule
        aq = qv.x + qv.y; as = si0 + si1; ae = esi0 + esi1;
    } else {                     // rare: flush atom 0 directly
        atomicAdd(&sum_q[mv.x],   qv.x);
        atomicAdd(&sum_si[mv.x],  si0);
        atomicAdd(&sum_esi[mv.x], esi0);
        aq = qv.y; as = si1; ae = esi1;
    }
    int m = mv.y;

    int lane = threadIdx.x & 63;
    #pragma unroll
    for (int off = 1; off < 64; off <<= 1) {
        int   om = __shfl_up(m,  off, 64);
        float oq = __shfl_up(aq, off, 64);
        float os = __shfl_up(as, off, 64);
        float oe = __shfl_up(ae, off, 64);
        if (lane >= off && om == m) { aq += oq; as += os; ae += oe; }
    }
    int nm = __shfl_down(m, 1, 64);
    if (lane == 63 || nm != m) {
        atomicAdd(&sum_q[m],   aq);
        atomicAdd(&sum_si[m],  as);
        atomicAdd(&sum_esi[m], ae);
    }
}

// Pass 2: per-molecule combine: t = (sum_q + sum_esi) / sum_si
__global__ __launch_bounds__(256) void ce_pass2(
    const float* __restrict__ sum_q, const float* __restrict__ sum_si,
    const float* __restrict__ sum_esi, float* __restrict__ t)
{
    int m = blockIdx.x * blockDim.x + threadIdx.x;
    t[m] = (sum_q[m] + sum_esi[m]) / sum_si[m];
}

// Pass 3 (proven round-3 version, ~10us): 4 atoms/thread, coalesced mol/out,
// h at 32B lane stride; t gather is sorted (wave-broadcast) and L2-resident.
__global__ __launch_bounds__(256) void ce_pass3(
    const float4* __restrict__ h4, const int4* __restrict__ mol4,
    const float* __restrict__ tmol, float4* __restrict__ out4)
{
    int g = blockIdx.x * 256 + threadIdx.x;   // over N_ATOMS/4
    int4   m4 = mol4[g];
    float4 hA = h4[g * 2];
    float4 hB = h4[g * 2 + 1];
    float4 o;
    o.x = (tmol[m4.x] - hA.x) / hA.y;
    o.y = (tmol[m4.y] - hA.z) / hA.w;
    o.z = (tmol[m4.z] - hB.x) / hB.y;
    o.w = (tmol[m4.w] - hB.z) / hB.w;
    out4[g] = o;
}

extern "C" void kernel_launch(void* const* d_in, const int* in_sizes, int n_in,
                              void* d_out, int out_size, void* d_ws, size_t ws_size,
                              hipStream_t stream) {
    const float4* h4   = (const float4*)d_in[0];
    const float2* q2   = (const float2*)d_in[1];
    const int2*   mol2 = (const int2*)d_in[2];
    const int4*   mol4 = (const int4*)d_in[2];
    float4* out4 = (float4*)d_out;

    float* sum_q   = (float*)d_ws;
    float* sum_si  = sum_q  + N_MOLS;
    float* sum_esi = sum_si + N_MOLS;
    float* tmol    = sum_esi + N_MOLS;

    hipMemsetAsync(d_ws, 0, (size_t)3 * N_MOLS * sizeof(float), stream);

    ce_pass1<<<N_ATOMS / 2 / 256, 256, 0, stream>>>(h4, q2, mol2,
                                                    sum_q, sum_si, sum_esi);
    ce_pass2<<<N_MOLS / 256, 256, 0, stream>>>(sum_q, sum_si, sum_esi, tmol);
    ce_pass3<<<N_ATOMS / 4 / 256, 256, 0, stream>>>(h4, mol4, tmol, out4);
}

// Round 9
// 55.279 us; speedup vs baseline: 9.8022x; 1.1159x over previous
//
#include <hip/hip_runtime.h>

#define N_ATOMS 8388608
#define N_MOLS  262144
#define N_PAIRS (N_ATOMS / 2)        // 4194304
#define HALF    (N_PAIRS / 2)        // 2097152 threads, chunk B at +HALF

// Pass 1: 2 pair-chunks per thread (A at g, B at g+HALF), each pair fully
// coalesced (h: float4/lane, q: float2, mol: int2). Per chunk: pair
// pre-combine (intra-pair boundary -> direct atomic flush of atom 0), then
// two INTERLEAVED 6-step segmented shuffle scans over lane partials
// (keys nondecreasing => equal keys contiguous => scan exact); segment tails
// flush. Only 2 accumulators: qe = q + e/s (only ever used summed) and si.
__global__ __launch_bounds__(256) void ce_pass1(
    const float4* __restrict__ h4, const float2* __restrict__ q2,
    const int2* __restrict__ mol2,
    float* __restrict__ sum_qe, float* __restrict__ sum_si)
{
    const int g = blockIdx.x * blockDim.x + threadIdx.x;   // 0 .. HALF-1
    const int tA = g, tB = g + HALF;

    // issue all loads up front (independent -> overlap)
    float4 hA = h4[tA];  float4 hB = h4[tB];
    float2 qA = q2[tA];  float2 qB = q2[tB];
    int2   mA = mol2[tA]; int2  mB = mol2[tB];

    // chunk A pair combine
    float siA0 = 1.0f / hA.y, siA1 = 1.0f / hA.w;
    float qeA0 = qA.x + hA.x * siA0, qeA1 = qA.y + hA.z * siA1;
    float aqeA, asiA;
    if (mA.x == mA.y) { aqeA = qeA0 + qeA1; asiA = siA0 + siA1; }
    else {
        atomicAdd(&sum_qe[mA.x], qeA0);
        atomicAdd(&sum_si[mA.x], siA0);
        aqeA = qeA1; asiA = siA1;
    }
    int mAk = mA.y;

    // chunk B pair combine
    float siB0 = 1.0f / hB.y, siB1 = 1.0f / hB.w;
    float qeB0 = qB.x + hB.x * siB0, qeB1 = qB.y + hB.z * siB1;
    float aqeB, asiB;
    if (mB.x == mB.y) { aqeB = qeB0 + qeB1; asiB = siB0 + siB1; }
    else {
        atomicAdd(&sum_qe[mB.x], qeB0);
        atomicAdd(&sum_si[mB.x], siB0);
        aqeB = qeB1; asiB = siB1;
    }
    int mBk = mB.y;

    const int lane = threadIdx.x & 63;
    // interleaved segmented inclusive scans (A and B independent)
    #pragma unroll
    for (int off = 1; off < 64; off <<= 1) {
        int   omA = __shfl_up(mAk,  off, 64);
        int   omB = __shfl_up(mBk,  off, 64);
        float oqA = __shfl_up(aqeA, off, 64);
        float oqB = __shfl_up(aqeB, off, 64);
        float osA = __shfl_up(asiA, off, 64);
        float osB = __shfl_up(asiB, off, 64);
        bool tkA = (lane >= off) && (omA == mAk);
        bool tkB = (lane >= off) && (omB == mBk);
        if (tkA) { aqeA += oqA; asiA += osA; }
        if (tkB) { aqeB += oqB; asiB += osB; }
    }
    int nmA = __shfl_down(mAk, 1, 64);
    int nmB = __shfl_down(mBk, 1, 64);
    if (lane == 63 || nmA != mAk) {
        atomicAdd(&sum_qe[mAk], aqeA);
        atomicAdd(&sum_si[mAk], asiA);
    }
    if (lane == 63 || nmB != mBk) {
        atomicAdd(&sum_qe[mBk], aqeB);
        atomicAdd(&sum_si[mBk], asiB);
    }
}

// Pass 2: t = sum_qe / sum_si
__global__ __launch_bounds__(256) void ce_pass2(
    const float* __restrict__ sum_qe, const float* __restrict__ sum_si,
    float* __restrict__ t)
{
    int m = blockIdx.x * blockDim.x + threadIdx.x;
    t[m] = sum_qe[m] / sum_si[m];
}

// Pass 3: 4 atoms/thread, coalesced mol/out; t gather sorted + L2-resident.
__global__ __launch_bounds__(256) void ce_pass3(
    const float4* __restrict__ h4, const int4* __restrict__ mol4,
    const float* __restrict__ tmol, float4* __restrict__ out4)
{
    int g = blockIdx.x * 256 + threadIdx.x;   // over N_ATOMS/4
    int4   m4 = mol4[g];
    float4 hA = h4[g * 2];
    float4 hB = h4[g * 2 + 1];
    float4 o;
    o.x = (tmol[m4.x] - hA.x) / hA.y;
    o.y = (tmol[m4.y] - hA.z) / hA.w;
    o.z = (tmol[m4.z] - hB.x) / hB.y;
    o.w = (tmol[m4.w] - hB.z) / hB.w;
    out4[g] = o;
}

extern "C" void kernel_launch(void* const* d_in, const int* in_sizes, int n_in,
                              void* d_out, int out_size, void* d_ws, size_t ws_size,
                              hipStream_t stream) {
    const float4* h4   = (const float4*)d_in[0];
    const float2* q2   = (const float2*)d_in[1];
    const int2*   mol2 = (const int2*)d_in[2];
    const int4*   mol4 = (const int4*)d_in[2];
    float4* out4 = (float4*)d_out;

    float* sum_qe = (float*)d_ws;
    float* sum_si = sum_qe + N_MOLS;
    float* tmol   = sum_si + N_MOLS;

    hipMemsetAsync(d_ws, 0, (size_t)2 * N_MOLS * sizeof(float), stream);

    ce_pass1<<<HALF / 256, 256, 0, stream>>>(h4, q2, mol2, sum_qe, sum_si);
    ce_pass2<<<N_MOLS / 256, 256, 0, stream>>>(sum_qe, sum_si, tmol);
    ce_pass3<<<N_ATOMS / 4 / 256, 256, 0, stream>>>(h4, mol4, tmol, out4);
}

// Round 10
// 54.684 us; speedup vs baseline: 9.9090x; 1.0109x over previous
//
#include <hip/hip_runtime.h>

#define N_ATOMS 8388608
#define N_MOLS  262144
#define N_PAIRS (N_ATOMS / 2)        // 4194304
#define HALF    (N_PAIRS / 2)        // 2097152 threads, chunk B at +HALF

// DPP helpers: cross-lane shift/broadcast in the VALU (no LDS pipe).
// bound_ctrl=false => lanes with invalid source (or rows masked off by RM)
// keep `old`: key old=-1 (never matches a real mol id), value old=0.
template<int CTRL, int RM>
__device__ __forceinline__ int dpp_key(int v) {
    return __builtin_amdgcn_update_dpp(-1, v, CTRL, RM, 0xf, false);
}
template<int CTRL, int RM>
__device__ __forceinline__ float dpp_val(float v) {
    return __int_as_float(
        __builtin_amdgcn_update_dpp(0, __float_as_int(v), CTRL, RM, 0xf, false));
}

// Pass 1: 2 pair-chunks per thread (A at g, B at g+HALF), coalesced loads
// (h: float4/lane, q: float2, mol: int2). Pair pre-combine (intra-pair
// boundary -> direct flush of atom 0), then a 6-step DPP segmented inclusive
// scan (row_shr:1/2/4/8 + row_bcast:15 + row_bcast:31) over lane partials —
// keys nondecreasing => equal keys contiguous => scan exact. Segment tails
// flush via native fp32 atomics (unsafeAtomicAdd -> global_atomic_add_f32).
__global__ __launch_bounds__(256) void ce_pass1(
    const float4* __restrict__ h4, const float2* __restrict__ q2,
    const int2* __restrict__ mol2,
    float* __restrict__ sum_qe, float* __restrict__ sum_si)
{
    const int g = blockIdx.x * blockDim.x + threadIdx.x;   // 0 .. HALF-1
    const int tA = g, tB = g + HALF;

    float4 hA = h4[tA];  float4 hB = h4[tB];
    float2 qA = q2[tA];  float2 qB = q2[tB];
    int2   mA = mol2[tA]; int2  mB = mol2[tB];

    // chunk A pair combine
    float siA0 = 1.0f / hA.y, siA1 = 1.0f / hA.w;
    float qeA0 = qA.x + hA.x * siA0, qeA1 = qA.y + hA.z * siA1;
    float aqeA, asiA;
    if (mA.x == mA.y) { aqeA = qeA0 + qeA1; asiA = siA0 + siA1; }
    else {
        unsafeAtomicAdd(&sum_qe[mA.x], qeA0);
        unsafeAtomicAdd(&sum_si[mA.x], siA0);
        aqeA = qeA1; asiA = siA1;
    }
    int mAk = mA.y;

    // chunk B pair combine
    float siB0 = 1.0f / hB.y, siB1 = 1.0f / hB.w;
    float qeB0 = qB.x + hB.x * siB0, qeB1 = qB.y + hB.z * siB1;
    float aqeB, asiB;
    if (mB.x == mB.y) { aqeB = qeB0 + qeB1; asiB = siB0 + siB1; }
    else {
        unsafeAtomicAdd(&sum_qe[mB.x], qeB0);
        unsafeAtomicAdd(&sum_si[mB.x], siB0);
        aqeB = qeB1; asiB = siB1;
    }
    int mBk = mB.y;

    // tail keys: issue the (only) bpermutes早 so their latency hides under scan
    int nmA = __shfl_down(mAk, 1, 64);
    int nmB = __shfl_down(mBk, 1, 64);

    // 6-step DPP segmented inclusive scan, both chunks interleaved (VALU-only)
#define SCAN_STEP(CTRL, RM)                                               \
    {                                                                     \
        int   kA  = dpp_key<CTRL, RM>(mAk);                               \
        int   kB  = dpp_key<CTRL, RM>(mBk);                               \
        float vqA = dpp_val<CTRL, RM>(aqeA);                              \
        float vsA = dpp_val<CTRL, RM>(asiA);                              \
        float vqB = dpp_val<CTRL, RM>(aqeB);                              \
        float vsB = dpp_val<CTRL, RM>(asiB);                              \
        if (kA == mAk) { aqeA += vqA; asiA += vsA; }                      \
        if (kB == mBk) { aqeB += vqB; asiB += vsB; }                      \
    }
    SCAN_STEP(0x111, 0xf)   // row_shr:1
    SCAN_STEP(0x112, 0xf)   // row_shr:2
    SCAN_STEP(0x114, 0xf)   // row_shr:4
    SCAN_STEP(0x118, 0xf)   // row_shr:8
    SCAN_STEP(0x142, 0xa)   // row_bcast:15 -> rows 1,3
    SCAN_STEP(0x143, 0xc)   // row_bcast:31 -> rows 2,3
#undef SCAN_STEP

    const int lane = threadIdx.x & 63;
    if (lane == 63 || nmA != mAk) {
        unsafeAtomicAdd(&sum_qe[mAk], aqeA);
        unsafeAtomicAdd(&sum_si[mAk], asiA);
    }
    if (lane == 63 || nmB != mBk) {
        unsafeAtomicAdd(&sum_qe[mBk], aqeB);
        unsafeAtomicAdd(&sum_si[mBk], asiB);
    }
}

// Pass 2: t = sum_qe / sum_si
__global__ __launch_bounds__(256) void ce_pass2(
    const float* __restrict__ sum_qe, const float* __restrict__ sum_si,
    float* __restrict__ t)
{
    int m = blockIdx.x * blockDim.x + threadIdx.x;
    t[m] = sum_qe[m] / sum_si[m];
}

// Pass 3: 4 atoms/thread, coalesced mol/out; t gather sorted + L2-resident.
__global__ __launch_bounds__(256) void ce_pass3(
    const float4* __restrict__ h4, const int4* __restrict__ mol4,
    const float* __restrict__ tmol, float4* __restrict__ out4)
{
    int g = blockIdx.x * 256 + threadIdx.x;   // over N_ATOMS/4
    int4   m4 = mol4[g];
    float4 hA = h4[g * 2];
    float4 hB = h4[g * 2 + 1];
    float4 o;
    o.x = (tmol[m4.x] - hA.x) / hA.y;
    o.y = (tmol[m4.y] - hA.z) / hA.w;
    o.z = (tmol[m4.z] - hB.x) / hB.y;
    o.w = (tmol[m4.w] - hB.z) / hB.w;
    out4[g] = o;
}

extern "C" void kernel_launch(void* const* d_in, const int* in_sizes, int n_in,
                              void* d_out, int out_size, void* d_ws, size_t ws_size,
                              hipStream_t stream) {
    const float4* h4   = (const float4*)d_in[0];
    const float2* q2   = (const float2*)d_in[1];
    const int2*   mol2 = (const int2*)d_in[2];
    const int4*   mol4 = (const int4*)d_in[2];
    float4* out4 = (float4*)d_out;

    float* sum_qe = (float*)d_ws;
    float* sum_si = sum_qe + N_MOLS;
    float* tmol   = sum_si + N_MOLS;

    hipMemsetAsync(d_ws, 0, (size_t)2 * N_MOLS * sizeof(float), stream);

    ce_pass1<<<HALF / 256, 256, 0, stream>>>(h4, q2, mol2, sum_qe, sum_si);
    ce_pass2<<<N_MOLS / 256, 256, 0, stream>>>(sum_qe, sum_si, tmol);
    ce_pass3<<<N_ATOMS / 4 / 256, 256, 0, stream>>>(h4, mol4, tmol, out4);
}